// Round 1
// baseline (422.159 us; speedup 1.0000x reference)
//
#include <hip/hip_runtime.h>
#include <math.h>

#define BB   4
#define CC   64
#define KK   64
#define DDim 16
#define HDim 64
#define WDim 64
#define SS   (DDim*HDim*WDim)   /* 65536 */
#define PLANE (HDim*WDim)       /* 4096  */
#define NCH1 256                /* gemm1 s-chunks per batch (chunk = 256) */
#define TOPN 6

// ---------------------------------------------------------------------------
// Kernel 1: depthwise 3x3x3 conv (SAME). blocks: t(0=q,1=k+v) x B x C.
// Each block walks the 16 d-planes with a 3-plane LDS ring (zero-padded halo).
// t==0 writes q into the d_out output-0 region (reused as scratch, later
// overwritten by gemm2); t==1 computes k and v from one x_kv read.
// ---------------------------------------------------------------------------
__global__ __launch_bounds__(256) void conv_qkv(
    const float* __restrict__ xq, const float* __restrict__ xkv,
    const float* __restrict__ wq, const float* __restrict__ bq,
    const float* __restrict__ wk, const float* __restrict__ bk,
    const float* __restrict__ wv, const float* __restrict__ bv,
    float* __restrict__ qout, float* __restrict__ kout, float* __restrict__ vout)
{
    const int PW = 68;                       // padded row stride (16B aligned rows)
    __shared__ float pl[3][66*68];
    int bid = blockIdx.x;
    int t = bid >> 8;                        // 0: q, 1: k+v
    int b = (bid >> 6) & 3;
    int c = bid & 63;
    int tid = threadIdx.x;

    const float* src = (t == 0 ? xq : xkv) + (size_t)(b*CC + c)*SS;
    float wA[27], wB[27], bA, bB;
    if (t == 0) {
        #pragma unroll
        for (int i = 0; i < 27; ++i) { wA[i] = wq[c*27 + i]; wB[i] = 0.f; }
        bA = bq[c]; bB = 0.f;
    } else {
        #pragma unroll
        for (int i = 0; i < 27; ++i) { wA[i] = wk[c*27 + i]; wB[i] = wv[c*27 + i]; }
        bA = bk[c]; bB = bv[c];
    }
    float* dstA = (t == 0 ? qout : kout) + (size_t)(b*CC + c)*SS;
    float* dstB = vout + (size_t)(b*CC + c)*SS;

    int h  = tid >> 2;            // 0..63
    int w0 = (tid & 3) << 4;      // 0,16,32,48 (strip of 16 outputs)

    auto load_plane = [&](int slot, int p) {
        float* dst = pl[slot];
        if (p < 0 || p >= DDim) {
            for (int i = tid; i < 66*66; i += 256) {
                int py = i / 66, px = i - py*66;
                dst[py*PW + px] = 0.f;
            }
        } else {
            const float* sp = src + p*PLANE;
            for (int i = tid; i < 66*66; i += 256) {
                int py = i / 66, px = i - py*66;
                int gy = py - 1, gx = px - 1;
                float v = 0.f;
                if (gy >= 0 && gy < HDim && gx >= 0 && gx < WDim) v = sp[gy*WDim + gx];
                dst[py*PW + px] = v;
            }
        }
    };

    load_plane(2, -1);   // plane -1 (zeros)
    load_plane(0, 0);    // plane 0
    for (int d = 0; d < DDim; ++d) {
        __syncthreads();                       // prev compute done reading ring
        load_plane((d + 1) % 3, d + 1);        // next plane (zeros if d+1==16)
        __syncthreads();

        float accA[16], accB[16];
        #pragma unroll
        for (int j = 0; j < 16; ++j) { accA[j] = bA; accB[j] = bB; }

        #pragma unroll
        for (int dz = 0; dz < 3; ++dz) {
            const float* plane = pl[(d + dz + 2) % 3];   // plane d+dz-1
            #pragma unroll
            for (int dy = 0; dy < 3; ++dy) {
                const float* row = &plane[(h + dy)*PW + w0];
                float r[18];
                float4 r0 = *(const float4*)&row[0];
                float4 r1 = *(const float4*)&row[4];
                float4 r2 = *(const float4*)&row[8];
                float4 r3 = *(const float4*)&row[12];
                r[0]=r0.x; r[1]=r0.y; r[2]=r0.z; r[3]=r0.w;
                r[4]=r1.x; r[5]=r1.y; r[6]=r1.z; r[7]=r1.w;
                r[8]=r2.x; r[9]=r2.y; r[10]=r2.z; r[11]=r2.w;
                r[12]=r3.x; r[13]=r3.y; r[14]=r3.z; r[15]=r3.w;
                r[16] = row[16]; r[17] = row[17];
                #pragma unroll
                for (int dx = 0; dx < 3; ++dx) {
                    float cA = wA[dz*9 + dy*3 + dx];
                    float cB = wB[dz*9 + dy*3 + dx];
                    #pragma unroll
                    for (int j = 0; j < 16; ++j) {
                        accA[j] = fmaf(cA, r[j+dx], accA[j]);
                        if (t) accB[j] = fmaf(cB, r[j+dx], accB[j]);
                    }
                }
            }
        }
        int off = d*PLANE + h*WDim + w0;
        *(float4*)&dstA[off+0]  = make_float4(accA[0],accA[1],accA[2],accA[3]);
        *(float4*)&dstA[off+4]  = make_float4(accA[4],accA[5],accA[6],accA[7]);
        *(float4*)&dstA[off+8]  = make_float4(accA[8],accA[9],accA[10],accA[11]);
        *(float4*)&dstA[off+12] = make_float4(accA[12],accA[13],accA[14],accA[15]);
        if (t) {
            *(float4*)&dstB[off+0]  = make_float4(accB[0],accB[1],accB[2],accB[3]);
            *(float4*)&dstB[off+4]  = make_float4(accB[4],accB[5],accB[6],accB[7]);
            *(float4*)&dstB[off+8]  = make_float4(accB[8],accB[9],accB[10],accB[11]);
            *(float4*)&dstB[off+12] = make_float4(accB[12],accB[13],accB[14],accB[15]);
        }
    }
}

// ---------------------------------------------------------------------------
// Kernel 2: attn partials. Per block: one batch, one 256-s chunk.
// LDS tiles stored [s][c] (pad 68) so inner loop reads are uniform-row
// ds_read_b128 (conflict-free broadcast groups). 128 threads, 4x8 per thread.
// ---------------------------------------------------------------------------
__global__ __launch_bounds__(128) void gemm1_qk(
    const float* __restrict__ q, const float* __restrict__ kk, float* __restrict__ part)
{
    __shared__ float qt[64][68];
    __shared__ float kt[64][68];
    int bid = blockIdx.x;
    int b  = bid >> 8;
    int ch = bid & 255;
    int tid = threadIdx.x;
    const float* qb = q  + (size_t)b*CC*SS;
    const float* kb = kk + (size_t)b*KK*SS;
    int c0  = (tid >> 3) * 4;     // 0..60
    int k0  = (tid & 7) * 8;      // 0..56
    int ls4 = (tid & 15) * 4;     // loader: s offset
    int lcg = tid >> 4;           // loader: c group 0..7
    float acc[4][8] = {};
    int sbase0 = ch * 256;
    for (int st = 0; st < 4; ++st) {
        int sb = sbase0 + st*64;
        __syncthreads();
        #pragma unroll
        for (int i = 0; i < 8; ++i) {
            int cc2 = lcg*8 + i;
            float4 qv = *(const float4*)&qb[cc2*SS + sb + ls4];
            float4 kv = *(const float4*)&kb[cc2*SS + sb + ls4];
            qt[ls4+0][cc2] = qv.x; qt[ls4+1][cc2] = qv.y; qt[ls4+2][cc2] = qv.z; qt[ls4+3][cc2] = qv.w;
            kt[ls4+0][cc2] = kv.x; kt[ls4+1][cc2] = kv.y; kt[ls4+2][cc2] = kv.z; kt[ls4+3][cc2] = kv.w;
        }
        __syncthreads();
        #pragma unroll 8
        for (int s = 0; s < 64; ++s) {
            float4 a  = *(const float4*)&qt[s][c0];
            float4 b0 = *(const float4*)&kt[s][k0];
            float4 b1 = *(const float4*)&kt[s][k0+4];
            float av[4] = {a.x, a.y, a.z, a.w};
            float bv[8] = {b0.x,b0.y,b0.z,b0.w,b1.x,b1.y,b1.z,b1.w};
            #pragma unroll
            for (int i = 0; i < 4; ++i)
                #pragma unroll
                for (int j = 0; j < 8; ++j)
                    acc[i][j] = fmaf(av[i], bv[j], acc[i][j]);
        }
    }
    float* pb = part + (size_t)(b*NCH1 + ch)*(CC*KK);
    #pragma unroll
    for (int i = 0; i < 4; ++i) {
        *(float4*)&pb[(c0+i)*KK + k0]     = make_float4(acc[i][0],acc[i][1],acc[i][2],acc[i][3]);
        *(float4*)&pb[(c0+i)*KK + k0 + 4] = make_float4(acc[i][4],acc[i][5],acc[i][6],acc[i][7]);
    }
}

// ---------------------------------------------------------------------------
// Kernel 3: reduce 256 chunk-partials -> attn logits (scaled 1/sqrt(K)=0.125)
// ---------------------------------------------------------------------------
__global__ __launch_bounds__(256) void reduce_attn(
    const float* __restrict__ part, float* __restrict__ attn)
{
    int bid = blockIdx.x;            // b*64 + c
    int b = bid >> 6, c = bid & 63;
    int tid = threadIdx.x;
    int k = tid & 63, g = tid >> 6;
    float s = 0.f;
    for (int ch = g; ch < NCH1; ch += 4)
        s += part[(size_t)(b*NCH1 + ch)*(CC*KK) + c*KK + k];
    __shared__ float red[256];
    red[tid] = s;
    __syncthreads();
    if (tid < 64) {
        float tot = red[tid] + red[tid+64] + red[tid+128] + red[tid+192];
        attn[b*CC*KK + c*KK + tid] = tot * 0.125f;
    }
}

// ---------------------------------------------------------------------------
// Kernel 4: per-batch softmax over K (rows) + top-6 mask per column over C.
// Strict ">" selection == lax.top_k lowest-index-first tie break. Writes
// attn_m (output 1) which gemm2 consumes.
// ---------------------------------------------------------------------------
__global__ __launch_bounds__(64) void softmax_topk(
    const float* __restrict__ attn, float* __restrict__ attn_m)
{
    __shared__ float p[64*65];
    int b = blockIdx.x;
    int t = threadIdx.x;
    for (int i = 0; i < 64; ++i) p[i*65 + t] = attn[b*4096 + i*64 + t];
    __syncthreads();
    // row softmax (row = t)
    float m = -1e30f;
    for (int k = 0; k < 64; ++k) m = fmaxf(m, p[t*65 + k]);
    float sum = 0.f;
    for (int k = 0; k < 64; ++k) { float e = expf(p[t*65+k] - m); p[t*65+k] = e; sum += e; }
    float inv = 1.f / sum;
    for (int k = 0; k < 64; ++k) p[t*65+k] *= inv;
    __syncthreads();
    // top-6 per column (column = t)
    unsigned long long chosen = 0ull;
    #pragma unroll
    for (int pass = 0; pass < TOPN; ++pass) {
        float best = -1.f; int bi = 0;
        for (int c2 = 0; c2 < 64; ++c2) {
            float v = p[c2*65 + t];
            if (!((chosen >> c2) & 1ull) && v > best) { best = v; bi = c2; }
        }
        chosen |= 1ull << bi;
    }
    for (int c2 = 0; c2 < 64; ++c2) {
        float v = p[c2*65 + t];
        attn_m[b*4096 + c2*64 + t] = ((chosen >> c2) & 1ull) ? v : 0.f;
    }
}

// ---------------------------------------------------------------------------
// Kernel 5: out = x_q + attn_m @ v. Per block: one batch, 512-s chunk
// (4 subtiles of 128). attn_m held transposed [k][c] in LDS for b128 reads.
// ---------------------------------------------------------------------------
__global__ __launch_bounds__(256) void gemm2_out(
    const float* __restrict__ attn_m, const float* __restrict__ v,
    const float* __restrict__ xq, float* __restrict__ out)
{
    __shared__ float amt[64][68];    // [k][c]
    __shared__ float vt[64][132];    // [k][s]
    int bid = blockIdx.x;
    int b  = bid >> 7;
    int ch = bid & 127;
    int tid = threadIdx.x;
    for (int i = 0; i < 16; ++i) {
        int idx = i*256 + tid;                 // idx = c*64 + k
        amt[idx & 63][idx >> 6] = attn_m[b*4096 + idx];
    }
    int c0 = (tid >> 4) * 4;      // 0..60
    int s0 = (tid & 15) * 8;      // 0..120
    const float* vb = v  + (size_t)b*KK*SS;
    const float* xb = xq + (size_t)b*CC*SS;
    float* ob = out + (size_t)b*CC*SS;
    int sb0 = ch * 512;
    for (int st = 0; st < 4; ++st) {
        int sb = sb0 + st*128;
        __syncthreads();
        #pragma unroll
        for (int i = 0; i < 8; ++i) {
            int k  = (tid >> 5)*8 + i;
            int s4 = (tid & 31)*4;
            *(float4*)&vt[k][s4] = *(const float4*)&vb[k*SS + sb + s4];
        }
        __syncthreads();
        float acc[4][8] = {};
        #pragma unroll 8
        for (int k = 0; k < 64; ++k) {
            float4 a  = *(const float4*)&amt[k][c0];
            float4 v0 = *(const float4*)&vt[k][s0];
            float4 v1 = *(const float4*)&vt[k][s0+4];
            float av[4] = {a.x,a.y,a.z,a.w};
            float vv[8] = {v0.x,v0.y,v0.z,v0.w,v1.x,v1.y,v1.z,v1.w};
            #pragma unroll
            for (int i = 0; i < 4; ++i)
                #pragma unroll
                for (int j = 0; j < 8; ++j)
                    acc[i][j] = fmaf(av[i], vv[j], acc[i][j]);
        }
        #pragma unroll
        for (int i = 0; i < 4; ++i) {
            int off = (c0+i)*SS + sb + s0;
            float4 x0 = *(const float4*)&xb[off];
            float4 x1 = *(const float4*)&xb[off+4];
            *(float4*)&ob[off]   = make_float4(acc[i][0]+x0.x, acc[i][1]+x0.y,
                                               acc[i][2]+x0.z, acc[i][3]+x0.w);
            *(float4*)&ob[off+4] = make_float4(acc[i][4]+x1.x, acc[i][5]+x1.y,
                                               acc[i][6]+x1.z, acc[i][7]+x1.w);
        }
    }
}

// ---------------------------------------------------------------------------
extern "C" void kernel_launch(void* const* d_in, const int* in_sizes, int n_in,
                              void* d_out, int out_size, void* d_ws, size_t ws_size,
                              hipStream_t stream)
{
    const float* xq  = (const float*)d_in[0];
    const float* xkv = (const float*)d_in[1];
    const float* wq  = (const float*)d_in[2];
    const float* bq  = (const float*)d_in[3];
    const float* wk  = (const float*)d_in[4];
    const float* bk  = (const float*)d_in[5];
    const float* wv  = (const float*)d_in[6];
    const float* bv  = (const float*)d_in[7];
    float* out = (float*)d_out;

    // workspace: k, v, gemm1 partials, attn logits  (~145 MiB)
    float* k_ws = (float*)d_ws;
    float* v_ws = k_ws + (size_t)BB*KK*SS;
    float* part = v_ws + (size_t)BB*KK*SS;
    float* attn = part + (size_t)BB*NCH1*CC*KK;

    float* q_store = out;                        // q lives in output-0 region,
                                                 // overwritten by gemm2_out
    float* attn_m  = out + (size_t)BB*CC*SS;     // output 1 (B*C*K floats)

    conv_qkv   <<<2*BB*CC,   256, 0, stream>>>(xq, xkv, wq, bq, wk, bk, wv, bv,
                                               q_store, k_ws, v_ws);
    gemm1_qk   <<<BB*NCH1,   128, 0, stream>>>(q_store, k_ws, part);
    reduce_attn<<<BB*CC,     256, 0, stream>>>(part, attn);
    softmax_topk<<<BB,        64, 0, stream>>>(attn, attn_m);
    gemm2_out  <<<BB*128,    256, 0, stream>>>(attn_m, v_ws, xq, out);
}

// Round 2
// 371.558 us; speedup vs baseline: 1.1362x; 1.1362x over previous
//
#include <hip/hip_runtime.h>
#include <math.h>

#define BB   4
#define CC   64
#define KK   64
#define DDim 16
#define HDim 64
#define WDim 64
#define SS   (DDim*HDim*WDim)   /* 65536 */
#define PLANE (HDim*WDim)       /* 4096  */
#define NCH1 256                /* gemm1 s-chunks per batch (chunk = 256) */
#define TOPN 6

// ---------------------------------------------------------------------------
// Kernel 1: depthwise 3x3x3 conv (SAME), direct-global version.
// One block per (t, b, c, d-plane): t=0 -> q, t=1 -> k, t=2 -> v.
// grid = 3*4*64*16 = 12288 blocks, 256 threads. No LDS, no barriers.
// Thread computes a 1x16 w-strip: 9 row-reads (4 float4 + 2 scalar), 432 FMA.
// Weights are block-uniform -> SGPRs. XCD-swizzled block ids so d-adjacent
// blocks of one (b,c) share an XCD L2 (3x dz plane reuse).
// ---------------------------------------------------------------------------
__global__ __launch_bounds__(256) void conv_one(
    const float* __restrict__ xq, const float* __restrict__ xkv,
    const float* __restrict__ wq, const float* __restrict__ bq,
    const float* __restrict__ wk, const float* __restrict__ bk,
    const float* __restrict__ wv, const float* __restrict__ bv,
    float* __restrict__ qout, float* __restrict__ kout, float* __restrict__ vout)
{
    // bijective XCD swizzle: 12288 blocks / 8 XCDs = 1536 contiguous works per XCD
    int bid  = blockIdx.x;
    int work = (bid & 7) * 1536 + (bid >> 3);
    int t    = work >> 12;            // 0:q 1:k 2:v
    int rem  = work & 4095;
    int b    = rem >> 10;
    int c    = (rem >> 4) & 63;
    int d    = rem & 15;

    const float* src; const float* wsel; const float* bsel; float* dst;
    if (t == 0)      { src = xq;  wsel = wq; bsel = bq; dst = qout; }
    else if (t == 1) { src = xkv; wsel = wk; bsel = bk; dst = kout; }
    else             { src = xkv; wsel = wv; bsel = bv; dst = vout; }
    src += (size_t)(b*CC + c) * SS;
    dst += (size_t)(b*CC + c) * SS;

    float wgt[27];
    #pragma unroll
    for (int i = 0; i < 27; ++i) wgt[i] = wsel[c*27 + i];   // uniform -> s_loads
    const float bias = bsel[c];

    const int tid = threadIdx.x;
    const int h   = tid >> 2;          // 0..63
    const int w0  = (tid & 3) << 4;    // 0,16,32,48

    float acc[16];
    #pragma unroll
    for (int j = 0; j < 16; ++j) acc[j] = bias;

    #pragma unroll
    for (int dz = 0; dz < 3; ++dz) {
        int p = d + dz - 1;
        if (p < 0 || p >= DDim) continue;          // wave-uniform branch
        #pragma unroll
        for (int dy = 0; dy < 3; ++dy) {
            int gy = h + dy - 1;
            if (gy < 0 || gy >= HDim) continue;    // divergent only at h=0/63
            const float* rp = src + p*PLANE + gy*WDim + w0;
            float rr[18];
            rr[0]  = (w0 > 0)  ? rp[-1] : 0.f;
            rr[17] = (w0 < 48) ? rp[16] : 0.f;
            float4 a0 = *(const float4*)(rp);
            float4 a1 = *(const float4*)(rp + 4);
            float4 a2 = *(const float4*)(rp + 8);
            float4 a3 = *(const float4*)(rp + 12);
            rr[1]=a0.x;  rr[2]=a0.y;  rr[3]=a0.z;  rr[4]=a0.w;
            rr[5]=a1.x;  rr[6]=a1.y;  rr[7]=a1.z;  rr[8]=a1.w;
            rr[9]=a2.x;  rr[10]=a2.y; rr[11]=a2.z; rr[12]=a2.w;
            rr[13]=a3.x; rr[14]=a3.y; rr[15]=a3.z; rr[16]=a3.w;
            #pragma unroll
            for (int dx = 0; dx < 3; ++dx) {
                const float cw = wgt[dz*9 + dy*3 + dx];
                #pragma unroll
                for (int j = 0; j < 16; ++j)
                    acc[j] = fmaf(cw, rr[j+dx], acc[j]);
            }
        }
    }

    const int off = d*PLANE + h*WDim + w0;
    *(float4*)&dst[off+0]  = make_float4(acc[0], acc[1], acc[2], acc[3]);
    *(float4*)&dst[off+4]  = make_float4(acc[4], acc[5], acc[6], acc[7]);
    *(float4*)&dst[off+8]  = make_float4(acc[8], acc[9], acc[10],acc[11]);
    *(float4*)&dst[off+12] = make_float4(acc[12],acc[13],acc[14],acc[15]);
}

// ---------------------------------------------------------------------------
// Kernel 2: attn partials. Per block: one batch, one 256-s chunk.
// LDS tiles stored [s][c] (pad 68) so inner loop reads are uniform-row
// ds_read_b128 (conflict-free broadcast groups). 128 threads, 4x8 per thread.
// ---------------------------------------------------------------------------
__global__ __launch_bounds__(128) void gemm1_qk(
    const float* __restrict__ q, const float* __restrict__ kk, float* __restrict__ part)
{
    __shared__ float qt[64][68];
    __shared__ float kt[64][68];
    int bid = blockIdx.x;
    int b  = bid >> 8;
    int ch = bid & 255;
    int tid = threadIdx.x;
    const float* qb = q  + (size_t)b*CC*SS;
    const float* kb = kk + (size_t)b*KK*SS;
    int c0  = (tid >> 3) * 4;     // 0..60
    int k0  = (tid & 7) * 8;      // 0..56
    int ls4 = (tid & 15) * 4;     // loader: s offset
    int lcg = tid >> 4;           // loader: c group 0..7
    float acc[4][8] = {};
    int sbase0 = ch * 256;
    for (int st = 0; st < 4; ++st) {
        int sb = sbase0 + st*64;
        __syncthreads();
        #pragma unroll
        for (int i = 0; i < 8; ++i) {
            int cc2 = lcg*8 + i;
            float4 qv = *(const float4*)&qb[cc2*SS + sb + ls4];
            float4 kv = *(const float4*)&kb[cc2*SS + sb + ls4];
            qt[ls4+0][cc2] = qv.x; qt[ls4+1][cc2] = qv.y; qt[ls4+2][cc2] = qv.z; qt[ls4+3][cc2] = qv.w;
            kt[ls4+0][cc2] = kv.x; kt[ls4+1][cc2] = kv.y; kt[ls4+2][cc2] = kv.z; kt[ls4+3][cc2] = kv.w;
        }
        __syncthreads();
        #pragma unroll 8
        for (int s = 0; s < 64; ++s) {
            float4 a  = *(const float4*)&qt[s][c0];
            float4 b0 = *(const float4*)&kt[s][k0];
            float4 b1 = *(const float4*)&kt[s][k0+4];
            float av[4] = {a.x, a.y, a.z, a.w};
            float bv[8] = {b0.x,b0.y,b0.z,b0.w,b1.x,b1.y,b1.z,b1.w};
            #pragma unroll
            for (int i = 0; i < 4; ++i)
                #pragma unroll
                for (int j = 0; j < 8; ++j)
                    acc[i][j] = fmaf(av[i], bv[j], acc[i][j]);
        }
    }
    float* pb = part + (size_t)(b*NCH1 + ch)*(CC*KK);
    #pragma unroll
    for (int i = 0; i < 4; ++i) {
        *(float4*)&pb[(c0+i)*KK + k0]     = make_float4(acc[i][0],acc[i][1],acc[i][2],acc[i][3]);
        *(float4*)&pb[(c0+i)*KK + k0 + 4] = make_float4(acc[i][4],acc[i][5],acc[i][6],acc[i][7]);
    }
}

// ---------------------------------------------------------------------------
// Kernel 3: reduce 256 chunk-partials -> attn logits (scaled 1/sqrt(K)=0.125)
// ---------------------------------------------------------------------------
__global__ __launch_bounds__(256) void reduce_attn(
    const float* __restrict__ part, float* __restrict__ attn)
{
    int bid = blockIdx.x;            // b*64 + c
    int b = bid >> 6, c = bid & 63;
    int tid = threadIdx.x;
    int k = tid & 63, g = tid >> 6;
    float s = 0.f;
    for (int ch = g; ch < NCH1; ch += 4)
        s += part[(size_t)(b*NCH1 + ch)*(CC*KK) + c*KK + k];
    __shared__ float red[256];
    red[tid] = s;
    __syncthreads();
    if (tid < 64) {
        float tot = red[tid] + red[tid+64] + red[tid+128] + red[tid+192];
        attn[b*CC*KK + c*KK + tid] = tot * 0.125f;
    }
}

// ---------------------------------------------------------------------------
// Kernel 4: per-batch softmax over K (rows) + top-6 mask per column over C.
// Strict ">" selection == lax.top_k lowest-index-first tie break. Writes
// attn_m (output 1) which gemm2 consumes.
// ---------------------------------------------------------------------------
__global__ __launch_bounds__(64) void softmax_topk(
    const float* __restrict__ attn, float* __restrict__ attn_m)
{
    __shared__ float p[64*65];
    int b = blockIdx.x;
    int t = threadIdx.x;
    for (int i = 0; i < 64; ++i) p[i*65 + t] = attn[b*4096 + i*64 + t];
    __syncthreads();
    // row softmax (row = t)
    float m = -1e30f;
    for (int k = 0; k < 64; ++k) m = fmaxf(m, p[t*65 + k]);
    float sum = 0.f;
    for (int k = 0; k < 64; ++k) { float e = expf(p[t*65+k] - m); p[t*65+k] = e; sum += e; }
    float inv = 1.f / sum;
    for (int k = 0; k < 64; ++k) p[t*65+k] *= inv;
    __syncthreads();
    // top-6 per column (column = t)
    unsigned long long chosen = 0ull;
    #pragma unroll
    for (int pass = 0; pass < TOPN; ++pass) {
        float best = -1.f; int bi = 0;
        for (int c2 = 0; c2 < 64; ++c2) {
            float v = p[c2*65 + t];
            if (!((chosen >> c2) & 1ull) && v > best) { best = v; bi = c2; }
        }
        chosen |= 1ull << bi;
    }
    for (int c2 = 0; c2 < 64; ++c2) {
        float v = p[c2*65 + t];
        attn_m[b*4096 + c2*64 + t] = ((chosen >> c2) & 1ull) ? v : 0.f;
    }
}

// ---------------------------------------------------------------------------
// Kernel 5: out = x_q + attn_m @ v. Per block: one batch, 512-s chunk
// (4 subtiles of 128). attn_m held transposed [k][c] in LDS for b128 reads.
// ---------------------------------------------------------------------------
__global__ __launch_bounds__(256) void gemm2_out(
    const float* __restrict__ attn_m, const float* __restrict__ v,
    const float* __restrict__ xq, float* __restrict__ out)
{
    __shared__ float amt[64][68];    // [k][c]
    __shared__ float vt[64][132];    // [k][s]
    int bid = blockIdx.x;
    int b  = bid >> 7;
    int ch = bid & 127;
    int tid = threadIdx.x;
    for (int i = 0; i < 16; ++i) {
        int idx = i*256 + tid;                 // idx = c*64 + k
        amt[idx & 63][idx >> 6] = attn_m[b*4096 + idx];
    }
    int c0 = (tid >> 4) * 4;      // 0..60
    int s0 = (tid & 15) * 8;      // 0..120
    const float* vb = v  + (size_t)b*KK*SS;
    const float* xb = xq + (size_t)b*CC*SS;
    float* ob = out + (size_t)b*CC*SS;
    int sb0 = ch * 512;
    for (int st = 0; st < 4; ++st) {
        int sb = sb0 + st*128;
        __syncthreads();
        #pragma unroll
        for (int i = 0; i < 8; ++i) {
            int k  = (tid >> 5)*8 + i;
            int s4 = (tid & 31)*4;
            *(float4*)&vt[k][s4] = *(const float4*)&vb[k*SS + sb + s4];
        }
        __syncthreads();
        float acc[4][8] = {};
        #pragma unroll 8
        for (int k = 0; k < 64; ++k) {
            float4 a  = *(const float4*)&amt[k][c0];
            float4 v0 = *(const float4*)&vt[k][s0];
            float4 v1 = *(const float4*)&vt[k][s0+4];
            float av[4] = {a.x,a.y,a.z,a.w};
            float vv[8] = {v0.x,v0.y,v0.z,v0.w,v1.x,v1.y,v1.z,v1.w};
            #pragma unroll
            for (int i = 0; i < 4; ++i)
                #pragma unroll
                for (int j = 0; j < 8; ++j)
                    acc[i][j] = fmaf(av[i], vv[j], acc[i][j]);
        }
        #pragma unroll
        for (int i = 0; i < 4; ++i) {
            int off = (c0+i)*SS + sb + s0;
            float4 x0 = *(const float4*)&xb[off];
            float4 x1 = *(const float4*)&xb[off+4];
            *(float4*)&ob[off]   = make_float4(acc[i][0]+x0.x, acc[i][1]+x0.y,
                                               acc[i][2]+x0.z, acc[i][3]+x0.w);
            *(float4*)&ob[off+4] = make_float4(acc[i][4]+x1.x, acc[i][5]+x1.y,
                                               acc[i][6]+x1.z, acc[i][7]+x1.w);
        }
    }
}

// ---------------------------------------------------------------------------
extern "C" void kernel_launch(void* const* d_in, const int* in_sizes, int n_in,
                              void* d_out, int out_size, void* d_ws, size_t ws_size,
                              hipStream_t stream)
{
    const float* xq  = (const float*)d_in[0];
    const float* xkv = (const float*)d_in[1];
    const float* wq  = (const float*)d_in[2];
    const float* bq  = (const float*)d_in[3];
    const float* wk  = (const float*)d_in[4];
    const float* bk  = (const float*)d_in[5];
    const float* wv  = (const float*)d_in[6];
    const float* bv  = (const float*)d_in[7];
    float* out = (float*)d_out;

    // workspace: k, v, gemm1 partials, attn logits  (~145 MiB)
    float* k_ws = (float*)d_ws;
    float* v_ws = k_ws + (size_t)BB*KK*SS;
    float* part = v_ws + (size_t)BB*KK*SS;
    float* attn = part + (size_t)BB*NCH1*CC*KK;

    float* q_store = out;                        // q lives in output-0 region,
                                                 // overwritten by gemm2_out
    float* attn_m  = out + (size_t)BB*CC*SS;     // output 1 (B*C*K floats)

    conv_one   <<<3*BB*CC*DDim, 256, 0, stream>>>(xq, xkv, wq, bq, wk, bk, wv, bv,
                                                  q_store, k_ws, v_ws);
    gemm1_qk   <<<BB*NCH1,   128, 0, stream>>>(q_store, k_ws, part);
    reduce_attn<<<BB*CC,     256, 0, stream>>>(part, attn);
    softmax_topk<<<BB,        64, 0, stream>>>(attn, attn_m);
    gemm2_out  <<<BB*128,    256, 0, stream>>>(attn_m, v_ws, xq, out);
}

// Round 3
// 241.187 us; speedup vs baseline: 1.7503x; 1.5405x over previous
//
#include <hip/hip_runtime.h>
#include <math.h>

#define BB   4
#define CC   64
#define KK   64
#define DDim 16
#define HDim 64
#define WDim 64
#define SS   (DDim*HDim*WDim)   /* 65536 */
#define PLANE (HDim*WDim)       /* 4096  */
#define NCH1 256                /* gemm1 s-chunks per batch (chunk = 256) */
#define TOPN 6

// ---------------------------------------------------------------------------
// Kernel 1: depthwise 3x3x3 conv (SAME), direct-global, register-tiled.
// One 128-thread block per (t, b, c, d-plane); t=0->q, 1->k, 2->v.
// Each thread: 4h x 8w outputs. Per dz-plane it loads a 6-row x 8w window as
// 2 aligned float4 per row (halo w0-1 / w0+8 fetched from neighbor lanes via
// __shfl), giving register-level dy reuse (rows used up to 3x) and 24-deep
// load MLP. No LDS, no barriers. Weights are block-uniform -> scalar loads.
// ---------------------------------------------------------------------------
__global__ __launch_bounds__(128, 3) void conv_one(
    const float* __restrict__ xq, const float* __restrict__ xkv,
    const float* __restrict__ wq, const float* __restrict__ bq,
    const float* __restrict__ wk, const float* __restrict__ bk,
    const float* __restrict__ wv, const float* __restrict__ bv,
    float* __restrict__ qout, float* __restrict__ kout, float* __restrict__ vout)
{
    // bijective XCD swizzle: 12288 blocks / 8 XCDs = 1536 contiguous per XCD
    int bid  = blockIdx.x;
    int work = (bid & 7) * 1536 + (bid >> 3);
    int t    = work >> 12;            // 0:q 1:k 2:v
    int rem  = work & 4095;
    int b    = rem >> 10;
    int c    = (rem >> 4) & 63;
    int d    = rem & 15;

    const float* src; const float* wsel; const float* bsel; float* dst;
    if (t == 0)      { src = xq;  wsel = wq; bsel = bq; dst = qout; }
    else if (t == 1) { src = xkv; wsel = wk; bsel = bk; dst = kout; }
    else             { src = xkv; wsel = wv; bsel = bv; dst = vout; }
    src += (size_t)(b*CC + c) * SS;
    dst += (size_t)(b*CC + c) * SS;

    float wgt[27];
    #pragma unroll
    for (int i = 0; i < 27; ++i) wgt[i] = wsel[c*27 + i];   // uniform
    const float bias = bsel[c];

    const int tid  = threadIdx.x;
    const int lane = tid & 63;
    const int wg   = tid & 7;         // w-group
    const int w0   = wg << 3;         // 0..56
    const int h0   = (tid >> 3) << 2; // 0..60

    float acc[4][8];
    #pragma unroll
    for (int i = 0; i < 4; ++i)
        #pragma unroll
        for (int j = 0; j < 8; ++j) acc[i][j] = bias;

    #pragma unroll
    for (int dz = 0; dz < 3; ++dz) {
        const int p = d + dz - 1;
        if (p < 0 || p >= DDim) continue;          // wave-uniform

        float r[6][10];
        // load 6 rows x 8 floats (2 x float4 each), all issued before use
        #pragma unroll
        for (int rr = 0; rr < 6; ++rr) {
            const int gy = h0 - 1 + rr;
            float4 a0 = make_float4(0.f,0.f,0.f,0.f);
            float4 a1 = a0;
            if (gy >= 0 && gy < HDim) {            // divergent only hg 0/15
                const float* bp = src + p*PLANE + gy*WDim + w0;
                a0 = *(const float4*)(bp);
                a1 = *(const float4*)(bp + 4);
            }
            r[rr][1]=a0.x; r[rr][2]=a0.y; r[rr][3]=a0.z; r[rr][4]=a0.w;
            r[rr][5]=a1.x; r[rr][6]=a1.y; r[rr][7]=a1.z; r[rr][8]=a1.w;
        }
        // halos from neighbor lanes (wg+-1 always within same wave)
        #pragma unroll
        for (int rr = 0; rr < 6; ++rr) {
            float lh = __shfl(r[rr][8], lane - 1, 64);
            float rh = __shfl(r[rr][1], lane + 1, 64);
            r[rr][0] = (wg > 0) ? lh : 0.f;
            r[rr][9] = (wg < 7) ? rh : 0.f;
        }
        // FMA: out-row i uses window rows i..i+2
        #pragma unroll
        for (int dy = 0; dy < 3; ++dy) {
            const float cw0 = wgt[dz*9 + dy*3 + 0];
            const float cw1 = wgt[dz*9 + dy*3 + 1];
            const float cw2 = wgt[dz*9 + dy*3 + 2];
            #pragma unroll
            for (int i = 0; i < 4; ++i) {
                #pragma unroll
                for (int j = 0; j < 8; ++j) {
                    float s = fmaf(cw0, r[i+dy][j], acc[i][j]);
                    s = fmaf(cw1, r[i+dy][j+1], s);
                    acc[i][j] = fmaf(cw2, r[i+dy][j+2], s);
                }
            }
        }
    }

    #pragma unroll
    for (int i = 0; i < 4; ++i) {
        const int off = d*PLANE + (h0+i)*WDim + w0;
        *(float4*)&dst[off]   = make_float4(acc[i][0],acc[i][1],acc[i][2],acc[i][3]);
        *(float4*)&dst[off+4] = make_float4(acc[i][4],acc[i][5],acc[i][6],acc[i][7]);
    }
}

// ---------------------------------------------------------------------------
// Kernel 2: attn partials. Per block: one batch, one 256-s chunk.
// LDS tiles stored [s][c] (pad 68) so inner loop reads are uniform-row
// ds_read_b128 (conflict-free broadcast groups). 128 threads, 4x8 per thread.
// ---------------------------------------------------------------------------
__global__ __launch_bounds__(128) void gemm1_qk(
    const float* __restrict__ q, const float* __restrict__ kk, float* __restrict__ part)
{
    __shared__ float qt[64][68];
    __shared__ float kt[64][68];
    int bid = blockIdx.x;
    int b  = bid >> 8;
    int ch = bid & 255;
    int tid = threadIdx.x;
    const float* qb = q  + (size_t)b*CC*SS;
    const float* kb = kk + (size_t)b*KK*SS;
    int c0  = (tid >> 3) * 4;     // 0..60
    int k0  = (tid & 7) * 8;      // 0..56
    int ls4 = (tid & 15) * 4;     // loader: s offset
    int lcg = tid >> 4;           // loader: c group 0..7
    float acc[4][8] = {};
    int sbase0 = ch * 256;
    for (int st = 0; st < 4; ++st) {
        int sb = sbase0 + st*64;
        __syncthreads();
        #pragma unroll
        for (int i = 0; i < 8; ++i) {
            int cc2 = lcg*8 + i;
            float4 qv = *(const float4*)&qb[cc2*SS + sb + ls4];
            float4 kv = *(const float4*)&kb[cc2*SS + sb + ls4];
            qt[ls4+0][cc2] = qv.x; qt[ls4+1][cc2] = qv.y; qt[ls4+2][cc2] = qv.z; qt[ls4+3][cc2] = qv.w;
            kt[ls4+0][cc2] = kv.x; kt[ls4+1][cc2] = kv.y; kt[ls4+2][cc2] = kv.z; kt[ls4+3][cc2] = kv.w;
        }
        __syncthreads();
        #pragma unroll 8
        for (int s = 0; s < 64; ++s) {
            float4 a  = *(const float4*)&qt[s][c0];
            float4 b0 = *(const float4*)&kt[s][k0];
            float4 b1 = *(const float4*)&kt[s][k0+4];
            float av[4] = {a.x, a.y, a.z, a.w};
            float bv[8] = {b0.x,b0.y,b0.z,b0.w,b1.x,b1.y,b1.z,b1.w};
            #pragma unroll
            for (int i = 0; i < 4; ++i)
                #pragma unroll
                for (int j = 0; j < 8; ++j)
                    acc[i][j] = fmaf(av[i], bv[j], acc[i][j]);
        }
    }
    float* pb = part + (size_t)(b*NCH1 + ch)*(CC*KK);
    #pragma unroll
    for (int i = 0; i < 4; ++i) {
        *(float4*)&pb[(c0+i)*KK + k0]     = make_float4(acc[i][0],acc[i][1],acc[i][2],acc[i][3]);
        *(float4*)&pb[(c0+i)*KK + k0 + 4] = make_float4(acc[i][4],acc[i][5],acc[i][6],acc[i][7]);
    }
}

// ---------------------------------------------------------------------------
// Kernel 3: reduce 256 chunk-partials -> attn logits (scaled 1/sqrt(K)=0.125)
// ---------------------------------------------------------------------------
__global__ __launch_bounds__(256) void reduce_attn(
    const float* __restrict__ part, float* __restrict__ attn)
{
    int bid = blockIdx.x;            // b*64 + c
    int b = bid >> 6, c = bid & 63;
    int tid = threadIdx.x;
    int k = tid & 63, g = tid >> 6;
    float s = 0.f;
    for (int ch = g; ch < NCH1; ch += 4)
        s += part[(size_t)(b*NCH1 + ch)*(CC*KK) + c*KK + k];
    __shared__ float red[256];
    red[tid] = s;
    __syncthreads();
    if (tid < 64) {
        float tot = red[tid] + red[tid+64] + red[tid+128] + red[tid+192];
        attn[b*CC*KK + c*KK + tid] = tot * 0.125f;
    }
}

// ---------------------------------------------------------------------------
// Kernel 4: per-batch softmax over K (rows) + top-6 mask per column over C.
// Strict ">" selection == lax.top_k lowest-index-first tie break. Writes
// attn_m (output 1) which gemm2 consumes.
// ---------------------------------------------------------------------------
__global__ __launch_bounds__(64) void softmax_topk(
    const float* __restrict__ attn, float* __restrict__ attn_m)
{
    __shared__ float p[64*65];
    int b = blockIdx.x;
    int t = threadIdx.x;
    for (int i = 0; i < 64; ++i) p[i*65 + t] = attn[b*4096 + i*64 + t];
    __syncthreads();
    // row softmax (row = t)
    float m = -1e30f;
    for (int k = 0; k < 64; ++k) m = fmaxf(m, p[t*65 + k]);
    float sum = 0.f;
    for (int k = 0; k < 64; ++k) { float e = expf(p[t*65+k] - m); p[t*65+k] = e; sum += e; }
    float inv = 1.f / sum;
    for (int k = 0; k < 64; ++k) p[t*65+k] *= inv;
    __syncthreads();
    // top-6 per column (column = t)
    unsigned long long chosen = 0ull;
    #pragma unroll
    for (int pass = 0; pass < TOPN; ++pass) {
        float best = -1.f; int bi = 0;
        for (int c2 = 0; c2 < 64; ++c2) {
            float v = p[c2*65 + t];
            if (!((chosen >> c2) & 1ull) && v > best) { best = v; bi = c2; }
        }
        chosen |= 1ull << bi;
    }
    for (int c2 = 0; c2 < 64; ++c2) {
        float v = p[c2*65 + t];
        attn_m[b*4096 + c2*64 + t] = ((chosen >> c2) & 1ull) ? v : 0.f;
    }
}

// ---------------------------------------------------------------------------
// Kernel 5: out = x_q + attn_m @ v. Per block: one batch, 512-s chunk
// (4 subtiles of 128). attn_m held transposed [k][c] in LDS for b128 reads.
// ---------------------------------------------------------------------------
__global__ __launch_bounds__(256) void gemm2_out(
    const float* __restrict__ attn_m, const float* __restrict__ v,
    const float* __restrict__ xq, float* __restrict__ out)
{
    __shared__ float amt[64][68];    // [k][c]
    __shared__ float vt[64][132];    // [k][s]
    int bid = blockIdx.x;
    int b  = bid >> 7;
    int ch = bid & 127;
    int tid = threadIdx.x;
    for (int i = 0; i < 16; ++i) {
        int idx = i*256 + tid;                 // idx = c*64 + k
        amt[idx & 63][idx >> 6] = attn_m[b*4096 + idx];
    }
    int c0 = (tid >> 4) * 4;      // 0..60
    int s0 = (tid & 15) * 8;      // 0..120
    const float* vb = v  + (size_t)b*KK*SS;
    const float* xb = xq + (size_t)b*CC*SS;
    float* ob = out + (size_t)b*CC*SS;
    int sb0 = ch * 512;
    for (int st = 0; st < 4; ++st) {
        int sb = sb0 + st*128;
        __syncthreads();
        #pragma unroll
        for (int i = 0; i < 8; ++i) {
            int k  = (tid >> 5)*8 + i;
            int s4 = (tid & 31)*4;
            *(float4*)&vt[k][s4] = *(const float4*)&vb[k*SS + sb + s4];
        }
        __syncthreads();
        float acc[4][8] = {};
        #pragma unroll 8
        for (int k = 0; k < 64; ++k) {
            float4 a  = *(const float4*)&amt[k][c0];
            float4 v0 = *(const float4*)&vt[k][s0];
            float4 v1 = *(const float4*)&vt[k][s0+4];
            float av[4] = {a.x,a.y,a.z,a.w};
            float vv[8] = {v0.x,v0.y,v0.z,v0.w,v1.x,v1.y,v1.z,v1.w};
            #pragma unroll
            for (int i = 0; i < 4; ++i)
                #pragma unroll
                for (int j = 0; j < 8; ++j)
                    acc[i][j] = fmaf(av[i], vv[j], acc[i][j]);
        }
        #pragma unroll
        for (int i = 0; i < 4; ++i) {
            int off = (c0+i)*SS + sb + s0;
            float4 x0 = *(const float4*)&xb[off];
            float4 x1 = *(const float4*)&xb[off+4];
            *(float4*)&ob[off]   = make_float4(acc[i][0]+x0.x, acc[i][1]+x0.y,
                                               acc[i][2]+x0.z, acc[i][3]+x0.w);
            *(float4*)&ob[off+4] = make_float4(acc[i][4]+x1.x, acc[i][5]+x1.y,
                                               acc[i][6]+x1.z, acc[i][7]+x1.w);
        }
    }
}

// ---------------------------------------------------------------------------
extern "C" void kernel_launch(void* const* d_in, const int* in_sizes, int n_in,
                              void* d_out, int out_size, void* d_ws, size_t ws_size,
                              hipStream_t stream)
{
    const float* xq  = (const float*)d_in[0];
    const float* xkv = (const float*)d_in[1];
    const float* wq  = (const float*)d_in[2];
    const float* bq  = (const float*)d_in[3];
    const float* wk  = (const float*)d_in[4];
    const float* bk  = (const float*)d_in[5];
    const float* wv  = (const float*)d_in[6];
    const float* bv  = (const float*)d_in[7];
    float* out = (float*)d_out;

    // workspace: k, v, gemm1 partials, attn logits  (~145 MiB)
    float* k_ws = (float*)d_ws;
    float* v_ws = k_ws + (size_t)BB*KK*SS;
    float* part = v_ws + (size_t)BB*KK*SS;
    float* attn = part + (size_t)BB*NCH1*CC*KK;

    float* q_store = out;                        // q lives in output-0 region,
                                                 // overwritten by gemm2_out
    float* attn_m  = out + (size_t)BB*CC*SS;     // output 1 (B*C*K floats)

    conv_one   <<<3*BB*CC*DDim, 128, 0, stream>>>(xq, xkv, wq, bq, wk, bk, wv, bv,
                                                  q_store, k_ws, v_ws);
    gemm1_qk   <<<BB*NCH1,   128, 0, stream>>>(q_store, k_ws, part);
    reduce_attn<<<BB*CC,     256, 0, stream>>>(part, attn);
    softmax_topk<<<BB,        64, 0, stream>>>(attn, attn_m);
    gemm2_out  <<<BB*128,    256, 0, stream>>>(attn_m, v_ws, xq, out);
}